// Round 1
// baseline (500.996 us; speedup 1.0000x reference)
//
#include <hip/hip_runtime.h>
#include <hip/hip_bf16.h>

#define LL 4096
#define FL 2049
#define DKN 128
#define DMOD 768

// ws layout (float units)
#define TW_OFF   0                         // 2048 float2 = 4096 floats
#define XT_OFF   4096                      // [2][2][128][4096] = 2097152 floats
#define SPEC_OFF (4096 + 2097152)          // [512][2049] float2 = 2098176 floats
#define Z_OFF    (SPEC_OFF + 2098176)      // [2][2][2049] = 8196 floats

// ---------------- twiddle table ----------------
__global__ void k_twiddle(float2* __restrict__ tw) {
    int j = blockIdx.x * 256 + threadIdx.x;
    if (j < 2048) {
        double a = -2.0 * 3.14159265358979323846 * (double)j / 4096.0;
        tw[j] = make_float2((float)cos(a), (float)sin(a));
    }
}

// ---------------- projection GEMM: out[b][d][l] = X[b][l][:] . W[d][:] + bias[d] ----------------
__global__ __launch_bounds__(256) void k_gemm1(const float* __restrict__ X,
                                               const float* __restrict__ W,
                                               const float* __restrict__ bias,
                                               float* __restrict__ out) {
    __shared__ float sX[16][64];
    __shared__ float sW[16][64];
    int b  = blockIdx.z;
    int l0 = blockIdx.x * 64;
    int d0 = blockIdx.y * 64;
    int t  = threadIdx.x;
    int lid = t >> 2, kq = (t & 3) * 4;
    int tx = t & 15, ty = t >> 4;
    const float* Xb = X + (size_t)b * LL * DMOD;
    float acc[4][4] = {};
    for (int k0 = 0; k0 < DMOD; k0 += 16) {
        float4 xv = *(const float4*)&Xb[(size_t)(l0 + lid) * DMOD + k0 + kq];
        float4 wv = *(const float4*)&W[(size_t)(d0 + lid) * DMOD + k0 + kq];
        sX[kq + 0][lid] = xv.x; sX[kq + 1][lid] = xv.y; sX[kq + 2][lid] = xv.z; sX[kq + 3][lid] = xv.w;
        sW[kq + 0][lid] = wv.x; sW[kq + 1][lid] = wv.y; sW[kq + 2][lid] = wv.z; sW[kq + 3][lid] = wv.w;
        __syncthreads();
#pragma unroll
        for (int k = 0; k < 16; k++) {
            float4 a = *(const float4*)&sX[k][tx * 4];
            float4 w = *(const float4*)&sW[k][ty * 4];
            acc[0][0] = fmaf(a.x, w.x, acc[0][0]); acc[0][1] = fmaf(a.x, w.y, acc[0][1]);
            acc[0][2] = fmaf(a.x, w.z, acc[0][2]); acc[0][3] = fmaf(a.x, w.w, acc[0][3]);
            acc[1][0] = fmaf(a.y, w.x, acc[1][0]); acc[1][1] = fmaf(a.y, w.y, acc[1][1]);
            acc[1][2] = fmaf(a.y, w.z, acc[1][2]); acc[1][3] = fmaf(a.y, w.w, acc[1][3]);
            acc[2][0] = fmaf(a.z, w.x, acc[2][0]); acc[2][1] = fmaf(a.z, w.y, acc[2][1]);
            acc[2][2] = fmaf(a.z, w.z, acc[2][2]); acc[2][3] = fmaf(a.z, w.w, acc[2][3]);
            acc[3][0] = fmaf(a.w, w.x, acc[3][0]); acc[3][1] = fmaf(a.w, w.y, acc[3][1]);
            acc[3][2] = fmaf(a.w, w.z, acc[3][2]); acc[3][3] = fmaf(a.w, w.w, acc[3][3]);
        }
        __syncthreads();
    }
#pragma unroll
    for (int j = 0; j < 4; j++) {
        int d = d0 + ty * 4 + j;
        float bb = bias[d];
        float4 r = make_float4(acc[0][j] + bb, acc[1][j] + bb, acc[2][j] + bb, acc[3][j] + bb);
        *(float4*)&out[((size_t)(b * DKN + d)) * LL + l0 + tx * 4] = r;
    }
}

// ---------------- radix-2 Stockham FFT (N=4096), fwd: real->spec[0..2048]; inv: spec*z -> real ----------------
template <int INV>
__global__ __launch_bounds__(256) void k_fft(const float* __restrict__ xin,
                                             float2* __restrict__ spec,
                                             const float* __restrict__ zsel,
                                             float* __restrict__ xout,
                                             const float2* __restrict__ tw) {
    __shared__ float2 bufA[4096];
    __shared__ float2 bufB[4096];
    int ser = blockIdx.x;   // (tensor*2+b)*128 + d
    int t   = threadIdx.x;
    if (!INV) {
        const float* x = xin + (size_t)ser * LL;
        for (int i = t; i < 4096; i += 256) bufA[i] = make_float2(x[i], 0.f);
    } else {
        const float2* sp = spec + (size_t)ser * FL;
        const float*  zz = zsel + (size_t)(ser >> 7) * FL;
        for (int f = t; f < FL; f += 256) {
            float2 v = sp[f];
            float  m = zz[f];
            float2 vm = make_float2(v.x * m, v.y * m);
            bufA[f] = vm;
            if (f > 0 && f < 2048) bufA[4096 - f] = make_float2(vm.x, -vm.y);
        }
    }
    __syncthreads();
    float2* src = bufA;
    float2* dst = bufB;
    for (int st = 0; st < 12; st++) {
        int m = 2048 >> st;
        for (int idx = t; idx < 2048; idx += 256) {
            int q = idx & ((1 << st) - 1);
            int p = idx >> st;
            float2 a  = src[q + (p << st)];
            float2 bb = src[q + ((p + m) << st)];
            float2 w  = tw[p << st];
            if (INV) w.y = -w.y;
            float2 s = make_float2(a.x + bb.x, a.y + bb.y);
            float2 d = make_float2(a.x - bb.x, a.y - bb.y);
            float2 dw = make_float2(d.x * w.x - d.y * w.y, d.x * w.y + d.y * w.x);
            dst[q + ((2 * p) << st)]     = s;
            dst[q + ((2 * p + 1) << st)] = dw;
        }
        __syncthreads();
        float2* tmp = src; src = dst; dst = tmp;
    }
    if (!INV) {
        float2* sp = spec + (size_t)ser * FL;
        for (int f = t; f < FL; f += 256) sp[f] = src[f];
    } else {
        float* xo = xout + (size_t)ser * LL;
        const float sc = 1.0f / 4096.0f;
        for (int i = t; i < 4096; i += 256) xo[i] = src[i].x * sc;
    }
}

// ---------------- selector MLP: z[tensor][b][f] ----------------
__global__ __launch_bounds__(64) void k_selector(const float2* __restrict__ spec,
                                                 const float* __restrict__ W1,
                                                 const float* __restrict__ b1,
                                                 const float* __restrict__ W2,
                                                 const float* __restrict__ b2,
                                                 const float* __restrict__ noise,
                                                 float* __restrict__ z,
                                                 int tensor) {
    int f = blockIdx.x;
    int b = blockIdx.y;
    int j = threadIdx.x;   // 0..63
    __shared__ __align__(16) float xr[128];
    const float2* sp = spec + (size_t)(tensor * 2 + b) * DKN * FL;
    xr[j]      = sp[(size_t)j * FL + f].x;
    xr[j + 64] = sp[(size_t)(j + 64) * FL + f].x;
    __syncthreads();
    float acc = b1[j];
    const float4* w4 = (const float4*)&W1[(size_t)j * 128];
    const float4* x4 = (const float4*)xr;
#pragma unroll
    for (int d4 = 0; d4 < 32; d4++) {
        float4 w = w4[d4];
        float4 x = x4[d4];
        acc = fmaf(x.x, w.x, acc);
        acc = fmaf(x.y, w.y, acc);
        acc = fmaf(x.z, w.z, acc);
        acc = fmaf(x.w, w.w, acc);
    }
    float h = fmaxf(acc, 0.f);
    float l0 = h * W2[j];
    float l1 = h * W2[64 + j];
#pragma unroll
    for (int off = 32; off >= 1; off >>= 1) {
        l0 += __shfl_down(l0, off);
        l1 += __shfl_down(l1, off);
    }
    if (j == 0) {
        l0 += b2[0];
        l1 += b2[1];
        const float* nz = noise + ((size_t)b * FL + f) * 2;
        float g0 = -logf(-logf(nz[0] + 1e-9f) + 1e-9f);
        float g1 = -logf(-logf(nz[1] + 1e-9f) + 1e-9f);
        float a0 = l0 + g0, a1 = l1 + g1;
        z[(size_t)(tensor * 2 + b) * FL + f] = 1.f / (1.f + expf(a0 - a1));
    }
}

// ---------------- scores GEMM: out[b][l][m] = (1/sqrt(128)) sum_d qf[b][d][l] kf[b][d][m] ----------------
__global__ __launch_bounds__(256) void k_scores(const float* __restrict__ xt,
                                                float* __restrict__ out) {
    __shared__ float sA[128][64];   // l tile
    __shared__ float sB[128][64];   // m tile
    int b  = blockIdx.z;
    int m0 = blockIdx.x * 64;
    int l0 = blockIdx.y * 64;
    const float* Ab = xt + (size_t)(b * DKN) * LL;          // qf (tensor 0)
    const float* Bb = xt + (size_t)((2 + b) * DKN) * LL;    // kf (tensor 1)
    int t = threadIdx.x;
    for (int i = t; i < 2048; i += 256) {
        int d  = i >> 4;
        int c4 = (i & 15) * 4;
        *(float4*)&sA[d][c4] = *(const float4*)&Ab[(size_t)d * LL + l0 + c4];
        *(float4*)&sB[d][c4] = *(const float4*)&Bb[(size_t)d * LL + m0 + c4];
    }
    __syncthreads();
    int tx = t & 15, ty = t >> 4;
    float acc[4][4] = {};
#pragma unroll 16
    for (int d = 0; d < 128; d++) {
        float4 av = *(const float4*)&sA[d][ty * 4];   // l components
        float4 bv = *(const float4*)&sB[d][tx * 4];   // m components
        acc[0][0] = fmaf(av.x, bv.x, acc[0][0]); acc[0][1] = fmaf(av.x, bv.y, acc[0][1]);
        acc[0][2] = fmaf(av.x, bv.z, acc[0][2]); acc[0][3] = fmaf(av.x, bv.w, acc[0][3]);
        acc[1][0] = fmaf(av.y, bv.x, acc[1][0]); acc[1][1] = fmaf(av.y, bv.y, acc[1][1]);
        acc[1][2] = fmaf(av.y, bv.z, acc[1][2]); acc[1][3] = fmaf(av.y, bv.w, acc[1][3]);
        acc[2][0] = fmaf(av.z, bv.x, acc[2][0]); acc[2][1] = fmaf(av.z, bv.y, acc[2][1]);
        acc[2][2] = fmaf(av.z, bv.z, acc[2][2]); acc[2][3] = fmaf(av.z, bv.w, acc[2][3]);
        acc[3][0] = fmaf(av.w, bv.x, acc[3][0]); acc[3][1] = fmaf(av.w, bv.y, acc[3][1]);
        acc[3][2] = fmaf(av.w, bv.z, acc[3][2]); acc[3][3] = fmaf(av.w, bv.w, acc[3][3]);
    }
    const float sc = 0.08838834764831843f;  // 1/sqrt(128)
#pragma unroll
    for (int i = 0; i < 4; i++) {
        int l = l0 + ty * 4 + i;
        float4 r = make_float4(acc[i][0] * sc, acc[i][1] * sc, acc[i][2] * sc, acc[i][3] * sc);
        *(float4*)&out[((size_t)(b * LL + l)) * LL + m0 + tx * 4] = r;
    }
}

// ---------------- masked softmax over rows of out, in place ----------------
__global__ __launch_bounds__(256) void k_softmax(float* __restrict__ out,
                                                 const int* __restrict__ mask) {
    int row = blockIdx.x;            // b*4096 + l
    int b   = row >> 12;
    float* p = out + (size_t)row * LL;
    const int* mk = mask + (size_t)b * LL;
    int t = threadIdx.x;
    float4 v[4];
    int4   mv[4];
    float mx = -3.0e38f;
#pragma unroll
    for (int c = 0; c < 4; c++) {
        int base = c * 1024 + t * 4;
        v[c]  = *(const float4*)&p[base];
        mv[c] = *(const int4*)&mk[base];
        if (mv[c].x) mx = fmaxf(mx, v[c].x);
        if (mv[c].y) mx = fmaxf(mx, v[c].y);
        if (mv[c].z) mx = fmaxf(mx, v[c].z);
        if (mv[c].w) mx = fmaxf(mx, v[c].w);
    }
    __shared__ float redm[4], reds[4];
    int wid = t >> 6, lane = t & 63;
#pragma unroll
    for (int off = 32; off >= 1; off >>= 1) mx = fmaxf(mx, __shfl_xor(mx, off));
    if (lane == 0) redm[wid] = mx;
    __syncthreads();
    mx = fmaxf(fmaxf(redm[0], redm[1]), fmaxf(redm[2], redm[3]));
    float sum = 0.f;
#pragma unroll
    for (int c = 0; c < 4; c++) {
        v[c].x = mv[c].x ? expf(v[c].x - mx) : 0.f;
        v[c].y = mv[c].y ? expf(v[c].y - mx) : 0.f;
        v[c].z = mv[c].z ? expf(v[c].z - mx) : 0.f;
        v[c].w = mv[c].w ? expf(v[c].w - mx) : 0.f;
        sum += v[c].x + v[c].y + v[c].z + v[c].w;
    }
#pragma unroll
    for (int off = 32; off >= 1; off >>= 1) sum += __shfl_xor(sum, off);
    if (lane == 0) reds[wid] = sum;
    __syncthreads();
    sum = reds[0] + reds[1] + reds[2] + reds[3];
    float inv = 1.0f / sum;
#pragma unroll
    for (int c = 0; c < 4; c++) {
        int base = c * 1024 + t * 4;
        float4 r = make_float4(v[c].x * inv, v[c].y * inv, v[c].z * inv, v[c].w * inv);
        *(float4*)&p[base] = r;
    }
}

extern "C" void kernel_launch(void* const* d_in, const int* in_sizes, int n_in,
                              void* d_out, int out_size, void* d_ws, size_t ws_size,
                              hipStream_t stream) {
    (void)in_sizes; (void)n_in; (void)out_size; (void)ws_size;
    const float* query  = (const float*)d_in[0];
    const float* key    = (const float*)d_in[1];
    const int*   mask   = (const int*)d_in[2];
    const float* Wq     = (const float*)d_in[3];
    const float* bq     = (const float*)d_in[4];
    const float* Wk     = (const float*)d_in[5];
    const float* bk     = (const float*)d_in[6];
    const float* qW1    = (const float*)d_in[7];
    const float* qb1    = (const float*)d_in[8];
    const float* qW2    = (const float*)d_in[9];
    const float* qb2    = (const float*)d_in[10];
    const float* kW1    = (const float*)d_in[11];
    const float* kb1    = (const float*)d_in[12];
    const float* kW2    = (const float*)d_in[13];
    const float* kb2    = (const float*)d_in[14];
    const float* qnoise = (const float*)d_in[15];
    const float* knoise = (const float*)d_in[16];

    float*  ws   = (float*)d_ws;
    float2* tw   = (float2*)(ws + TW_OFF);
    float*  xt   = ws + XT_OFF;                 // [tensor][b][d][l]
    float2* spec = (float2*)(ws + SPEC_OFF);    // [tensor*2+b][d][2049]
    float*  zsel = ws + Z_OFF;                  // [tensor][b][2049]
    float*  out  = (float*)d_out;

    k_twiddle<<<dim3(8), dim3(256), 0, stream>>>(tw);
    k_gemm1<<<dim3(64, 2, 2), dim3(256), 0, stream>>>(query, Wq, bq, xt);
    k_gemm1<<<dim3(64, 2, 2), dim3(256), 0, stream>>>(key, Wk, bk, xt + (size_t)2 * DKN * LL);
    k_fft<0><<<dim3(512), dim3(256), 0, stream>>>(xt, spec, nullptr, nullptr, tw);
    k_selector<<<dim3(FL, 2), dim3(64), 0, stream>>>(spec, qW1, qb1, qW2, qb2, qnoise, zsel, 0);
    k_selector<<<dim3(FL, 2), dim3(64), 0, stream>>>(spec, kW1, kb1, kW2, kb2, knoise, zsel, 1);
    k_fft<1><<<dim3(512), dim3(256), 0, stream>>>(nullptr, spec, zsel, xt, tw);
    k_scores<<<dim3(64, 64, 2), dim3(256), 0, stream>>>(xt, out);
    k_softmax<<<dim3(8192), dim3(256), 0, stream>>>(out, mask);
}

// Round 2
// 404.442 us; speedup vs baseline: 1.2387x; 1.2387x over previous
//
#include <hip/hip_runtime.h>
#include <hip/hip_bf16.h>

#define LL 4096
#define FL 2049
#define DKN 128
#define DMOD 768

// ws layout (float units)
#define TW_OFF   0                         // 2048 float2 = 4096 floats
#define XT_OFF   4096                      // [2][2][128][4096] = 2097152 floats
#define SPEC_OFF (4096 + 2097152)          // [512][2049] float2 = 2098176 floats
#define Z_OFF    (SPEC_OFF + 2098176)      // [2][2][2049] = 8196 floats
// xtb (bf16 [4][4096][128] = 4MB) aliases the spec region (dead after irfft)

using bf16x8 = __attribute__((ext_vector_type(8))) short;
using f32x4  = __attribute__((ext_vector_type(4))) float;

__device__ __forceinline__ float2 cmul(float2 a, float2 b) {
    return make_float2(a.x * b.x - a.y * b.y, a.x * b.y + a.y * b.x);
}
__device__ __forceinline__ int SWZ(int a) { return a ^ ((a >> 4) & 15); }
__device__ __forceinline__ ushort f2bf(float f) {
    __hip_bfloat16 h = __float2bfloat16(f);
    return *(ushort*)&h;
}

// ---------------- twiddle table ----------------
__global__ void k_twiddle(float2* __restrict__ tw) {
    int j = blockIdx.x * 256 + threadIdx.x;
    if (j < 2048) {
        double a = -2.0 * 3.14159265358979323846 * (double)j / 4096.0;
        tw[j] = make_float2((float)cos(a), (float)sin(a));
    }
}

// ---------------- projection GEMM: out[b][d][l] = X[b][l][:] . W[d][:] + bias[d] ----------------
__global__ __launch_bounds__(256) void k_gemm1(const float* __restrict__ X,
                                               const float* __restrict__ W,
                                               const float* __restrict__ bias,
                                               float* __restrict__ out) {
    __shared__ float sX[16][64];
    __shared__ float sW[16][64];
    int b  = blockIdx.z;
    int l0 = blockIdx.x * 64;
    int d0 = blockIdx.y * 64;
    int t  = threadIdx.x;
    int lid = t >> 2, kq = (t & 3) * 4;
    int tx = t & 15, ty = t >> 4;
    const float* Xb = X + (size_t)b * LL * DMOD;
    float acc[4][4] = {};
    for (int k0 = 0; k0 < DMOD; k0 += 16) {
        float4 xv = *(const float4*)&Xb[(size_t)(l0 + lid) * DMOD + k0 + kq];
        float4 wv = *(const float4*)&W[(size_t)(d0 + lid) * DMOD + k0 + kq];
        sX[kq + 0][lid] = xv.x; sX[kq + 1][lid] = xv.y; sX[kq + 2][lid] = xv.z; sX[kq + 3][lid] = xv.w;
        sW[kq + 0][lid] = wv.x; sW[kq + 1][lid] = wv.y; sW[kq + 2][lid] = wv.z; sW[kq + 3][lid] = wv.w;
        __syncthreads();
#pragma unroll
        for (int k = 0; k < 16; k++) {
            float4 a = *(const float4*)&sX[k][tx * 4];
            float4 w = *(const float4*)&sW[k][ty * 4];
            acc[0][0] = fmaf(a.x, w.x, acc[0][0]); acc[0][1] = fmaf(a.x, w.y, acc[0][1]);
            acc[0][2] = fmaf(a.x, w.z, acc[0][2]); acc[0][3] = fmaf(a.x, w.w, acc[0][3]);
            acc[1][0] = fmaf(a.y, w.x, acc[1][0]); acc[1][1] = fmaf(a.y, w.y, acc[1][1]);
            acc[1][2] = fmaf(a.y, w.z, acc[1][2]); acc[1][3] = fmaf(a.y, w.w, acc[1][3]);
            acc[2][0] = fmaf(a.z, w.x, acc[2][0]); acc[2][1] = fmaf(a.z, w.y, acc[2][1]);
            acc[2][2] = fmaf(a.z, w.z, acc[2][2]); acc[2][3] = fmaf(a.z, w.w, acc[2][3]);
            acc[3][0] = fmaf(a.w, w.x, acc[3][0]); acc[3][1] = fmaf(a.w, w.y, acc[3][1]);
            acc[3][2] = fmaf(a.w, w.z, acc[3][2]); acc[3][3] = fmaf(a.w, w.w, acc[3][3]);
        }
        __syncthreads();
    }
#pragma unroll
    for (int j = 0; j < 4; j++) {
        int d = d0 + ty * 4 + j;
        float bb = bias[d];
        float4 r = make_float4(acc[0][j] + bb, acc[1][j] + bb, acc[2][j] + bb, acc[3][j] + bb);
        *(float4*)&out[((size_t)(b * DKN + d)) * LL + l0 + tx * 4] = r;
    }
}

// ---------------- radix-4 in-place Stockham FFT (N=4096), swizzled LDS ----------------
// fwd: real->spec[0..2048]; inv: spec*z -> real (scaled 1/N)
template <int INV>
__global__ __launch_bounds__(512) void k_fft4(const float* __restrict__ xin,
                                              float2* __restrict__ spec,
                                              const float* __restrict__ zsel,
                                              float* __restrict__ xout,
                                              const float2* __restrict__ tw) {
    __shared__ float2 buf[4096];
    int ser = blockIdx.x;   // (tensor*2+b)*128 + d
    int t   = threadIdx.x;
    if (!INV) {
        const float* x = xin + (size_t)ser * LL;
        for (int i = t; i < 4096; i += 512) buf[SWZ(i)] = make_float2(x[i], 0.f);
    } else {
        const float2* sp = spec + (size_t)ser * FL;
        const float*  zz = zsel + (size_t)(ser >> 7) * FL;
        for (int f = t; f < FL; f += 512) {
            float2 v = sp[f];
            float  m = zz[f];
            float2 vm = make_float2(v.x * m, v.y * m);
            buf[SWZ(f)] = vm;
            if (f > 0 && f < 2048) buf[SWZ(4096 - f)] = make_float2(vm.x, -vm.y);
        }
    }
    __syncthreads();
#pragma unroll
    for (int st = 0; st < 6; st++) {
        int Lm1 = (1 << (2 * st)) - 1;
        float2 x0[2], x1[2], x2[2], x3[2];
#pragma unroll
        for (int ii = 0; ii < 2; ii++) {
            int idx = t + 512 * ii;
            x0[ii] = buf[SWZ(idx)];
            x1[ii] = buf[SWZ(idx + 1024)];
            x2[ii] = buf[SWZ(idx + 2048)];
            x3[ii] = buf[SWZ(idx + 3072)];
        }
        __syncthreads();
#pragma unroll
        for (int ii = 0; ii < 2; ii++) {
            int idx = t + 512 * ii;
            int q = idx & Lm1;
            int r = idx - q;              // p * L
            int wbase = q + (r << 2);     // q + 4*p*L
            int L = Lm1 + 1;
            float2 a0 = x0[ii], a1 = x1[ii], a2 = x2[ii], a3 = x3[ii];
            float2 t0 = make_float2(a0.x + a2.x, a0.y + a2.y);
            float2 t1 = make_float2(a0.x - a2.x, a0.y - a2.y);
            float2 t2 = make_float2(a1.x + a3.x, a1.y + a3.y);
            float2 t3 = make_float2(a1.x - a3.x, a1.y - a3.y);
            float2 y0 = make_float2(t0.x + t2.x, t0.y + t2.y);
            float2 y2 = make_float2(t0.x - t2.x, t0.y - t2.y);
            float2 y1, y3;
            if (!INV) {
                y1 = make_float2(t1.x + t3.y, t1.y - t3.x);
                y3 = make_float2(t1.x - t3.y, t1.y + t3.x);
            } else {
                y1 = make_float2(t1.x - t3.y, t1.y + t3.x);
                y3 = make_float2(t1.x + t3.y, t1.y - t3.x);
            }
            float2 w1 = tw[r];
            float2 w2 = tw[2 * r];
            if (INV) { w1.y = -w1.y; w2.y = -w2.y; }
            float2 w3 = cmul(w1, w2);
            buf[SWZ(wbase)]         = y0;
            buf[SWZ(wbase + L)]     = cmul(y1, w1);
            buf[SWZ(wbase + 2 * L)] = cmul(y2, w2);
            buf[SWZ(wbase + 3 * L)] = cmul(y3, w3);
        }
        __syncthreads();
    }
    if (!INV) {
        float2* sp = spec + (size_t)ser * FL;
        for (int f = t; f < FL; f += 512) sp[f] = buf[SWZ(f)];
    } else {
        float* xo = xout + (size_t)ser * LL;
        const float sc = 1.0f / 4096.0f;
        for (int i = t; i < 4096; i += 512) xo[i] = buf[SWZ(i)].x * sc;
    }
}

// ---------------- selector MLP: z[tensor][b][f] ----------------
__global__ __launch_bounds__(64) void k_selector(const float2* __restrict__ spec,
                                                 const float* __restrict__ W1,
                                                 const float* __restrict__ b1,
                                                 const float* __restrict__ W2,
                                                 const float* __restrict__ b2,
                                                 const float* __restrict__ noise,
                                                 float* __restrict__ z,
                                                 int tensor) {
    int f = blockIdx.x;
    int b = blockIdx.y;
    int j = threadIdx.x;   // 0..63
    __shared__ __align__(16) float xr[128];
    const float2* sp = spec + (size_t)(tensor * 2 + b) * DKN * FL;
    xr[j]      = sp[(size_t)j * FL + f].x;
    xr[j + 64] = sp[(size_t)(j + 64) * FL + f].x;
    __syncthreads();
    float acc = b1[j];
    const float4* w4 = (const float4*)&W1[(size_t)j * 128];
    const float4* x4 = (const float4*)xr;
#pragma unroll
    for (int d4 = 0; d4 < 32; d4++) {
        float4 w = w4[d4];
        float4 x = x4[d4];
        acc = fmaf(x.x, w.x, acc);
        acc = fmaf(x.y, w.y, acc);
        acc = fmaf(x.z, w.z, acc);
        acc = fmaf(x.w, w.w, acc);
    }
    float h = fmaxf(acc, 0.f);
    float l0 = h * W2[j];
    float l1 = h * W2[64 + j];
#pragma unroll
    for (int off = 32; off >= 1; off >>= 1) {
        l0 += __shfl_down(l0, off);
        l1 += __shfl_down(l1, off);
    }
    if (j == 0) {
        l0 += b2[0];
        l1 += b2[1];
        const float* nz = noise + ((size_t)b * FL + f) * 2;
        float g0 = -logf(-logf(nz[0] + 1e-9f) + 1e-9f);
        float g1 = -logf(-logf(nz[1] + 1e-9f) + 1e-9f);
        float a0 = l0 + g0, a1 = l1 + g1;
        z[(size_t)(tensor * 2 + b) * FL + f] = 1.f / (1.f + expf(a0 - a1));
    }
}

// ---------------- transpose fp32 [tb][d][l] -> bf16 [tb][l][d] ----------------
__global__ __launch_bounds__(256) void k_tr(const float* __restrict__ xt,
                                            ushort* __restrict__ xtb) {
    __shared__ float s[64][129];
    int tb = blockIdx.y;            // 0..3
    int l0 = blockIdx.x * 64;
    int t  = threadIdx.x;
    const float* g = xt + (size_t)tb * DKN * LL;
    int d = t >> 1, c0 = (t & 1) * 32;
#pragma unroll
    for (int j4 = 0; j4 < 8; j4++) {
        float4 v = *(const float4*)&g[(size_t)d * LL + l0 + c0 + j4 * 4];
        s[c0 + j4 * 4 + 0][d] = v.x;
        s[c0 + j4 * 4 + 1][d] = v.y;
        s[c0 + j4 * 4 + 2][d] = v.z;
        s[c0 + j4 * 4 + 3][d] = v.w;
    }
    __syncthreads();
    int l = t >> 2, dc0 = (t & 3) * 32;
    ushort* o = xtb + (size_t)tb * LL * DKN + (size_t)(l0 + l) * DKN + dc0;
#pragma unroll
    for (int c8 = 0; c8 < 4; c8++) {
        union { ushort us[8]; uint4 v; } pk;
#pragma unroll
        for (int u = 0; u < 8; u++) pk.us[u] = f2bf(s[l][dc0 + c8 * 8 + u]);
        *(uint4*)&o[c8 * 8] = pk.v;
    }
}

// ---------------- scores GEMM (bf16 MFMA): out[b][l][m] = (1/sqrt(128)) sum_d qf[l][d] kf[m][d] ----------------
__global__ __launch_bounds__(256) void k_scores_mfma(const ushort* __restrict__ xtb,
                                                     float* __restrict__ out) {
    int b  = blockIdx.z;
    int m0 = blockIdx.x * 128;
    int l0 = blockIdx.y * 128;
    int wid  = threadIdx.x >> 6;
    int lane = threadIdx.x & 63;
    int wr = wid >> 1, wc = wid & 1;
    const ushort* A = xtb + (size_t)b * LL * DKN;        // qf [l][d]
    const ushort* B = xtb + (size_t)(2 + b) * LL * DKN;  // kf [m][d]
    int arow = l0 + wr * 64 + (lane & 15);
    int brow = m0 + wc * 64 + (lane & 15);
    int kcol = (lane >> 4) * 8;
    f32x4 acc[4][4] = {};
#pragma unroll
    for (int kk = 0; kk < 4; kk++) {
        bf16x8 af[4], bf[4];
#pragma unroll
        for (int mt = 0; mt < 4; mt++)
            af[mt] = *(const bf16x8*)&A[(size_t)(arow + mt * 16) * DKN + kk * 32 + kcol];
#pragma unroll
        for (int nt = 0; nt < 4; nt++)
            bf[nt] = *(const bf16x8*)&B[(size_t)(brow + nt * 16) * DKN + kk * 32 + kcol];
#pragma unroll
        for (int mt = 0; mt < 4; mt++)
#pragma unroll
            for (int nt = 0; nt < 4; nt++)
                acc[mt][nt] = __builtin_amdgcn_mfma_f32_16x16x32_bf16(af[mt], bf[nt], acc[mt][nt], 0, 0, 0);
    }
    const float sc = 0.08838834764831843f;  // 1/sqrt(128)
    int rg = lane >> 4, cl = lane & 15;
#pragma unroll
    for (int mt = 0; mt < 4; mt++) {
#pragma unroll
        for (int r = 0; r < 4; r++) {
            int l = l0 + wr * 64 + mt * 16 + rg * 4 + r;
            float* orow = out + ((size_t)(b * LL + l)) * LL + m0 + wc * 64 + cl;
#pragma unroll
            for (int nt = 0; nt < 4; nt++)
                orow[nt * 16] = acc[mt][nt][r] * sc;
        }
    }
}

// ---------------- masked softmax over rows of out, in place ----------------
__global__ __launch_bounds__(256) void k_softmax(float* __restrict__ out,
                                                 const int* __restrict__ mask) {
    int row = blockIdx.x;            // b*4096 + l
    int b   = row >> 12;
    float* p = out + (size_t)row * LL;
    const int* mk = mask + (size_t)b * LL;
    int t = threadIdx.x;
    float4 v[4];
    int4   mv[4];
    float mx = -3.0e38f;
#pragma unroll
    for (int c = 0; c < 4; c++) {
        int base = c * 1024 + t * 4;
        v[c]  = *(const float4*)&p[base];
        mv[c] = *(const int4*)&mk[base];
        if (mv[c].x) mx = fmaxf(mx, v[c].x);
        if (mv[c].y) mx = fmaxf(mx, v[c].y);
        if (mv[c].z) mx = fmaxf(mx, v[c].z);
        if (mv[c].w) mx = fmaxf(mx, v[c].w);
    }
    __shared__ float redm[4], reds[4];
    int wid = t >> 6, lane = t & 63;
#pragma unroll
    for (int off = 32; off >= 1; off >>= 1) mx = fmaxf(mx, __shfl_xor(mx, off));
    if (lane == 0) redm[wid] = mx;
    __syncthreads();
    mx = fmaxf(fmaxf(redm[0], redm[1]), fmaxf(redm[2], redm[3]));
    float sum = 0.f;
#pragma unroll
    for (int c = 0; c < 4; c++) {
        v[c].x = mv[c].x ? expf(v[c].x - mx) : 0.f;
        v[c].y = mv[c].y ? expf(v[c].y - mx) : 0.f;
        v[c].z = mv[c].z ? expf(v[c].z - mx) : 0.f;
        v[c].w = mv[c].w ? expf(v[c].w - mx) : 0.f;
        sum += v[c].x + v[c].y + v[c].z + v[c].w;
    }
#pragma unroll
    for (int off = 32; off >= 1; off >>= 1) sum += __shfl_xor(sum, off);
    if (lane == 0) reds[wid] = sum;
    __syncthreads();
    sum = reds[0] + reds[1] + reds[2] + reds[3];
    float inv = 1.0f / sum;
#pragma unroll
    for (int c = 0; c < 4; c++) {
        int base = c * 1024 + t * 4;
        float4 r = make_float4(v[c].x * inv, v[c].y * inv, v[c].z * inv, v[c].w * inv);
        *(float4*)&p[base] = r;
    }
}

extern "C" void kernel_launch(void* const* d_in, const int* in_sizes, int n_in,
                              void* d_out, int out_size, void* d_ws, size_t ws_size,
                              hipStream_t stream) {
    (void)in_sizes; (void)n_in; (void)out_size; (void)ws_size;
    const float* query  = (const float*)d_in[0];
    const float* key    = (const float*)d_in[1];
    const int*   mask   = (const int*)d_in[2];
    const float* Wq     = (const float*)d_in[3];
    const float* bq     = (const float*)d_in[4];
    const float* Wk     = (const float*)d_in[5];
    const float* bk     = (const float*)d_in[6];
    const float* qW1    = (const float*)d_in[7];
    const float* qb1    = (const float*)d_in[8];
    const float* qW2    = (const float*)d_in[9];
    const float* qb2    = (const float*)d_in[10];
    const float* kW1    = (const float*)d_in[11];
    const float* kb1    = (const float*)d_in[12];
    const float* kW2    = (const float*)d_in[13];
    const float* kb2    = (const float*)d_in[14];
    const float* qnoise = (const float*)d_in[15];
    const float* knoise = (const float*)d_in[16];

    float*  ws   = (float*)d_ws;
    float2* tw   = (float2*)(ws + TW_OFF);
    float*  xt   = ws + XT_OFF;                 // [tensor][b][d][l] fp32
    float2* spec = (float2*)(ws + SPEC_OFF);    // [tensor*2+b][d][2049]
    ushort* xtb  = (ushort*)(ws + SPEC_OFF);    // bf16 [tb][l][d], aliases spec (dead after irfft)
    float*  zsel = ws + Z_OFF;                  // [tensor][b][2049]
    float*  out  = (float*)d_out;

    k_twiddle<<<dim3(8), dim3(256), 0, stream>>>(tw);
    k_gemm1<<<dim3(64, 2, 2), dim3(256), 0, stream>>>(query, Wq, bq, xt);
    k_gemm1<<<dim3(64, 2, 2), dim3(256), 0, stream>>>(key, Wk, bk, xt + (size_t)2 * DKN * LL);
    k_fft4<0><<<dim3(512), dim3(512), 0, stream>>>(xt, spec, nullptr, nullptr, tw);
    k_selector<<<dim3(FL, 2), dim3(64), 0, stream>>>(spec, qW1, qb1, qW2, qb2, qnoise, zsel, 0);
    k_selector<<<dim3(FL, 2), dim3(64), 0, stream>>>(spec, kW1, kb1, kW2, kb2, knoise, zsel, 1);
    k_fft4<1><<<dim3(512), dim3(512), 0, stream>>>(nullptr, spec, zsel, xt, tw);
    k_tr<<<dim3(64, 4), dim3(256), 0, stream>>>(xt, xtb);
    k_scores_mfma<<<dim3(32, 32, 2), dim3(256), 0, stream>>>(xtb, out);
    k_softmax<<<dim3(8192), dim3(256), 0, stream>>>(out, mask);
}